// Round 12
// baseline (201.571 us; speedup 1.0000x reference)
//
#include <hip/hip_runtime.h>
#include <math.h>

#define B_   32
#define N_   128
#define H_   100
#define ROWS (B_ * N_)    // 4096
#define RH   (ROWS * H_)  // 409600
#define OUTSZ (B_ * H_)   // 3200

typedef __attribute__((ext_vector_type(2))) float v2f;

__device__ __forceinline__ v2f pkfma(v2f a, v2f b, v2f c) {
    return __builtin_elementwise_fma(a, b, c);   // v_pk_fma_f32
}

// ---------------------------------------------------------------------------
// K1: hw = nodes@Ww (initial hv computed in-register by pass 1). Also zeroes
// out[]. r12: packed-fp32 over k-pairs (v_pk_fma_f32, half the VALU issue).
__global__ __launch_bounds__(256, 6) void k_proj0(const float* __restrict__ nodes,
                                                  const float* __restrict__ Ww,
                                                  float* __restrict__ hw,
                                                  float* __restrict__ out) {
    __shared__ float nod_s[2][H_];
    const int row0 = blockIdx.x * 2;
    const int t = threadIdx.x, r = t >> 7, j = t & 127;
    {
        const int gid = blockIdx.x * 256 + t;
        if (gid < OUTSZ) out[gid] = 0.f;
    }
    {
        const float4* ng = (const float4*)(nodes + (size_t)row0 * H_);
        if (t < 50) ((float4*)nod_s)[t] = ng[t];
    }
    __syncthreads();
    if (j >= H_) return;
    const float* hp = nod_s[r];
    v2f w2a = {0.f, 0.f};
#pragma unroll 10
    for (int k = 0; k < H_; k += 2) {
        const v2f h2 = *(const v2f*)&hp[k];                  // LDS b64 broadcast
        const v2f w2 = {Ww[k * H_ + j], Ww[(k + 1) * H_ + j]};
        w2a = pkfma(h2, w2, w2a);
    }
    hw[(size_t)(row0 + r) * H_ + j] = w2a.x + w2a.y;
}

// ---------------------------------------------------------------------------
// K2 (r12): r0 geometry exactly (2048 x 256, batch-affine swizzle, global
// hww, direct weight loads). NEW: every inner loop packed fp32 (VOP3P
// v_pk_fma_f32) -- message loop over w-pairs, GEMMs over k-pairs, proj's
// va/wa fused into one packed accumulator. Rationale: 12 rounds left two
// invariants -- pass time ~51us and VALU ISSUE ~22us (VALUBusy x dur) --
// with every memory-side lever null. Packing halves the issue count
// (~1800 -> ~900 instr/thread): if issue is co-binding, pass -> ~43us;
// if flat, VALU is exonerated and the wall is pure memory latency.
// e_s stored as packed component planes (exy/ezw float4, broadcast reads);
// per-edge mask stored as float in LDS (kills per-iter SGPR shift+cndmask).
template <int MODE, int INIT_HV>
__global__ __launch_bounds__(256, 6) void k_pass(const float* __restrict__ edges,
                                                 const float* __restrict__ We,
                                                 const float* __restrict__ Wu,
                                                 const float* __restrict__ Wv,
                                                 const float* __restrict__ Ww,
                                                 const float* __restrict__ Wr,
                                                 const float* __restrict__ nodes,
                                                 float* __restrict__ hv_io,
                                                 const float* __restrict__ hw_in,
                                                 float* __restrict__ hw_out,
                                                 const float* __restrict__ hid_in,
                                                 float* __restrict__ hidden,
                                                 float* __restrict__ out) {
    __shared__ float4 exy_s[2][N_ / 2];    // (ex[2q],ex[2q+1],ey[2q],ey[2q+1])
    __shared__ float4 ezw_s[2][N_ / 2];    // (ez.., ew..)
    __shared__ float  m_s[2][N_];          // per-edge mask as float
    __shared__ float  asum_part[4];
    __shared__ float  hid_s[2][H_];
    __shared__ float  msg_s[2][H_];
    __shared__ float  hn_s[2][H_];
    __shared__ float  nod_s[2][H_];        // MODE 2 only
    __shared__ float  red_s[2][H_];        // MODE 2 only

    // batch-affine swizzle: co-resident blocks (≡ mod 256) share batch b
    const int bx = blockIdx.x;
    const int cu = bx & 255, slot = bx >> 8;
    const int b = cu >> 3;
    const int vt = (cu & 7) + slot * 8;
    const int row0 = b * N_ + vt * 2;

    const int t = threadIdx.x, r = t >> 7, j = t & 127;
    const int wv = t >> 6, lane = t & 63;
    const int row = row0 + r;
    const bool act = (j < H_);

    {   // stage both rows' edges into packed planes; mask floats; row sums
        const float4* eg = (const float4*)(edges + (size_t)row0 * N_ * 4);
        const float4 e = eg[t];                   // t == r*128 + j, coalesced
        const int q = j >> 1, h = j & 1;
        float* exy = (float*)&exy_s[r][q];
        float* ezw = (float*)&ezw_s[r][q];
        exy[h]     = e.x;
        exy[2 + h] = e.y;
        ezw[h]     = e.z;
        ezw[2 + h] = e.w;
        float s = (e.x + e.y) + (e.z + e.w);
        m_s[r][j] = (s != 0.f) ? 1.f : 0.f;
#pragma unroll
        for (int off = 32; off > 0; off >>= 1) s += __shfl_down(s, off);
        if (lane == 0) asum_part[wv] = s;
    }
    {   // stage pre-update hidden rows (50 float4); nodes too if readout pass
        const float4* hg = (const float4*)(hid_in + (size_t)row0 * H_);
        if (t < 50) ((float4*)hid_s)[t] = hg[t];
        if (MODE == 2) {
            const float4* ng = (const float4*)(nodes + (size_t)row0 * H_);
            if (t < 50) ((float4*)nod_s)[t] = ng[t];
        }
    }
    __syncthreads();

    const float nm = ((asum_part[2 * r] + asum_part[2 * r + 1]) != 0.f) ? 1.f : 0.f;

    if (act) {
        float hvv;
        if (INIT_HV) {      // pass 1: hv = hid @ Wv, packed over k-pairs
            const float* hp = hid_s[r];
            v2f v2a = {0.f, 0.f};
#pragma unroll 10
            for (int k = 0; k < H_; k += 2) {
                const v2f h2 = *(const v2f*)&hp[k];
                const v2f w2 = {Wv[k * H_ + j], Wv[(k + 1) * H_ + j]};
                v2a = pkfma(h2, w2, v2a);
            }
            hvv = v2a.x + v2a.y;
        } else {
            hvv = hv_io[(size_t)row * H_ + j];
        }
        const v2f we0_2 = {We[0 * H_ + j], We[0 * H_ + j]};
        const v2f we1_2 = {We[1 * H_ + j], We[1 * H_ + j]};
        const v2f we2_2 = {We[2 * H_ + j], We[2 * H_ + j]};
        const v2f we3_2 = {We[3 * H_ + j], We[3 * H_ + j]};
        const v2f hv2 = {hvv, hvv};
        const v2f zero2 = {0.f, 0.f};
        const float* hwp = hw_in + (size_t)b * N_ * H_ + j;
        v2f acc2 = {0.f, 0.f};
#pragma unroll 8
        for (int q = 0; q < N_ / 2; ++q) {        // w-pairs (2q, 2q+1)
            const int w = q * 2;
            const float a0 = hwp[(size_t)w * H_];         // coalesced global
            const float a1 = hwp[(size_t)(w + 1) * H_];
            const float4 v1 = exy_s[r][q];        // LDS b128 broadcast
            const float4 v2 = ezw_s[r][q];
            const v2f m2 = *(const v2f*)&m_s[r][w];       // LDS b64 broadcast
            v2f p2 = hv2 + (v2f){a0, a1};                 // v_pk_add_f32
            p2 = pkfma((v2f){v1.x, v1.y}, we0_2, p2);
            p2 = pkfma((v2f){v1.z, v1.w}, we1_2, p2);
            p2 = pkfma((v2f){v2.x, v2.y}, we2_2, p2);
            p2 = pkfma((v2f){v2.z, v2.w}, we3_2, p2);
            p2 = __builtin_elementwise_max(p2, zero2);    // v_pk_max_f32
            acc2 = pkfma(m2, p2, acc2);
        }
        msg_s[r][j] = acc2.x + acc2.y;
    }
    __syncthreads();

    if (act) {
        const float* hp = hid_s[r];
        const float* mp = msg_s[r];
        v2f u2 = {0.f, 0.f};
#pragma unroll 10
        for (int k = 0; k < H_; k += 2) {
            const v2f h2 = *(const v2f*)&hp[k];
            const v2f w2 = {Wu[k * H_ + j], Wu[(k + 1) * H_ + j]};
            u2 = pkfma(h2, w2, u2);
        }
#pragma unroll 10
        for (int k = 0; k < H_; k += 2) {
            const v2f m2v = *(const v2f*)&mp[k];
            const v2f w2 = {Wu[(H_ + k) * H_ + j], Wu[(H_ + k + 1) * H_ + j]};
            u2 = pkfma(m2v, w2, u2);
        }
        const float u = u2.x + u2.y;
        const float nh = (nm != 0.f) ? tanhf(u) : hid_s[r][j];
        hn_s[r][j] = nh;
        if (MODE == 1) hidden[(size_t)row * H_ + j] = nh;
    }
    __syncthreads();

    if (MODE == 1) {        // next pass's hv/hw: va/wa fused in one packed acc
        if (act) {
            const float* hp = hn_s[r];
            v2f vw2 = {0.f, 0.f};                 // (va, wa)
#pragma unroll 10
            for (int k = 0; k < H_; ++k) {
                const float h = hp[k];            // LDS b32 broadcast
                const v2f w2 = {Wv[k * H_ + j], Ww[k * H_ + j]};
                vw2 = pkfma((v2f){h, h}, w2, vw2);
            }
            hv_io[(size_t)row * H_ + j] = vw2.x;  // row-local: safe in-place
            hw_out[(size_t)row * H_ + j] = vw2.y; // double-buffered
        }
    } else {                // MODE 2: fused readout, packed over k-pairs
        if (act) {
            const float* hp = hn_s[r];
            const float* np = nod_s[r];
            v2f u2 = {0.f, 0.f};
#pragma unroll 10
            for (int k = 0; k < H_; k += 2) {
                const v2f h2 = *(const v2f*)&hp[k];
                const v2f w2 = {Wr[k * H_ + j], Wr[(k + 1) * H_ + j]};
                u2 = pkfma(h2, w2, u2);
            }
#pragma unroll 10
            for (int k = 0; k < H_; k += 2) {
                const v2f n2 = *(const v2f*)&np[k];
                const v2f w2 = {Wr[(H_ + k) * H_ + j], Wr[(H_ + k + 1) * H_ + j]};
                u2 = pkfma(n2, w2, u2);
            }
            red_s[r][j] = nm * fmaxf(u2.x + u2.y, 0.f);
        }
        __syncthreads();
        if (t < H_) atomicAdd(out + b * H_ + t, red_s[0][t] + red_s[1][t]);
    }
}

// ---------------------------------------------------------------------------
extern "C" void kernel_launch(void* const* d_in, const int* in_sizes, int n_in,
                              void* d_out, int out_size, void* d_ws, size_t ws_size,
                              hipStream_t stream) {
    const float* nodes = (const float*)d_in[0];
    const float* edges = (const float*)d_in[1];
    const float* Wv    = (const float*)d_in[2];
    const float* Ww    = (const float*)d_in[3];
    const float* We    = (const float*)d_in[4];
    const float* Wu    = (const float*)d_in[5];
    const float* Wr    = (const float*)d_in[6];
    float* out = (float*)d_out;

    float* hidden = (float*)d_ws;     // RH
    float* hv     = hidden + RH;      // RH
    float* hwA    = hv + RH;          // RH
    float* hwB    = hwA + RH;         // RH

    k_proj0<<<ROWS / 2, 256, 0, stream>>>(nodes, Ww, hwA, out);

    k_pass<1, 1><<<ROWS / 2, 256, 0, stream>>>(edges, We, Wu, Wv, Ww, Wr, nodes,
                                               hv, hwA, hwB, nodes, hidden, out);
    k_pass<1, 0><<<ROWS / 2, 256, 0, stream>>>(edges, We, Wu, Wv, Ww, Wr, nodes,
                                               hv, hwB, hwA, hidden, hidden, out);
    k_pass<2, 0><<<ROWS / 2, 256, 0, stream>>>(edges, We, Wu, Wv, Ww, Wr, nodes,
                                               hv, hwA, hwB, hidden, hidden, out);
}